// Round 4
// baseline (231.756 us; speedup 1.0000x reference)
//
#include <hip/hip_runtime.h>
#include <hip/hip_bf16.h>
#include <cstdint>

// Problem constants
#define NWORDS 16384   // B*S
#define NCH    20      // chars per word
#define CEDIM  32      // char emb dim
#define WEDIM  512     // output channels
#define WPB    8       // words per block
#define NBLK   (NWORDS/WPB)   // 2048

typedef __attribute__((ext_vector_type(8))) short bf16x8;
typedef __attribute__((ext_vector_type(4))) float f32x4;

__device__ __forceinline__ unsigned short f2bf(float f){
    union { float f; unsigned int u; } v; v.f = f;
    unsigned int u = v.u + 0x7fffu + ((v.u >> 16) & 1u);
    return (unsigned short)(u >> 16);
}

// Prep: wbf[o][k*32+i] = bf16(cnn[o][i][k]); cembbf[c][i] = bf16(cemb[c][i])
// + zero row at c=256 (for t=16 tile padding); bias[o] = sum_k cnn[o][32][k]
__global__ __launch_bounds__(256) void prep_kernel(const float* __restrict__ cnn,
                                                   const float* __restrict__ cemb,
                                                   unsigned short* __restrict__ wbf,
                                                   unsigned short* __restrict__ cembbf,
                                                   float* __restrict__ bias){
    int idx = blockIdx.x * 256 + threadIdx.x;
    if (idx < WEDIM*128){
        int o = idx >> 7, kk = idx & 127;
        int k = kk >> 5, i = kk & 31;
        wbf[idx] = f2bf(cnn[o*132 + i*4 + k]);
    } else if (idx < WEDIM*128 + 256*CEDIM){
        int j = idx - WEDIM*128;
        cembbf[j] = f2bf(cemb[j]);
    } else if (idx < WEDIM*128 + 256*CEDIM + CEDIM){
        int j = idx - WEDIM*128;
        cembbf[j] = 0;                       // zero row (char id 256)
    } else if (idx < WEDIM*128 + 257*CEDIM + WEDIM){
        int o = idx - (WEDIM*128 + 257*CEDIM);
        const float* p = cnn + o*132 + 128;
        bias[o] = p[0] + p[1] + p[2] + p[3];
    }
}

// waves_per_eu(4): cap unified VGPR+AGPR at 128/wave -> 4 waves/SIMD.
// Round 3 was 116 VGPR + ~56 AGPR = 172 (just over the 170 3-wave line)
// -> 2 waves/SIMD and 55% all-wave stall. This version streams A/B
// fragments per K-step to fit: ~81 VGPR + 40 AGPR live.
__global__ __attribute__((amdgpu_waves_per_eu(4))) __launch_bounds__(256)
void conv_kernel(
    const int* __restrict__ data,              // [16384]
    const int* __restrict__ spelling,          // [50000][20]
    const unsigned short* __restrict__ cembbf, // [257][32] bf16 (row 256 = 0)
    const unsigned short* __restrict__ wbf,    // [512][128] bf16 (kk' = k*32+i)
    const float* __restrict__ bias,            // [512]
    float* __restrict__ out)                   // [16384][512] f32
{
    __shared__ int scid[WPB*NCH];
    const int tid   = threadIdx.x;
    const int wbase = blockIdx.x * WPB;

    if (tid < WPB*NCH){
        int w = tid / NCH, j = tid - w*NCH;
        scid[tid] = spelling[data[wbase + w]*NCH + j];
    }
    __syncthreads();

    const int l  = tid & 63;
    const int wv = tid >> 6;
    const int wy = wv >> 1, wx = wv & 1;     // wy: word-half, wx: 32-col half
    const int lr = l & 15, lq = l >> 4;
    const int lqoff = lq * 16;               // byte offset within a 64B emb row
    const int colw  = wx * 32;

    const char* cb = (const char*)cembbf;
    const char* wb = (const char*)wbf;

    // Packed char ids: word w = wy*4+mi, positions lr..lr+3 (one byte each)
    unsigned int pk[4];
    #pragma unroll
    for (int mi = 0; mi < 4; ++mi){
        const int* sp = &scid[(wy*4 + mi)*NCH + lr];
        pk[mi] = (unsigned)sp[0] | ((unsigned)sp[1] << 8) |
                 ((unsigned)sp[2] << 16) | ((unsigned)sp[3] << 24);
    }
    // t=16 tile voffsets (rows 8..15 -> zero row 256)
    int voffX[4];
    #pragma unroll
    for (int q = 0; q < 4; ++q){
        int ch = (lr < 8) ? scid[(lr & 7)*NCH + 16 + q] : 256;
        voffX[q] = ch*64 + lqoff;
    }
    // B row voffsets (bytes): row = colw + ni*16 + lr, 256 B/row
    int vB[2];
    #pragma unroll
    for (int ni = 0; ni < 2; ++ni) vB[ni] = (colw + ni*16 + lr)*256 + lqoff;

    // ---- software-pipelined s = cc*4 + q loop ----
    bf16x8 afb[2][4], axb[2], bb[2][2];
    #pragma unroll
    for (int mi = 0; mi < 4; ++mi)
        afb[0][mi] = *reinterpret_cast<const bf16x8*>(cb + ((pk[mi]) & 0xFFu)*64 + lqoff);
    axb[0] = *reinterpret_cast<const bf16x8*>(cb + voffX[0]);
    bb[0][0] = *reinterpret_cast<const bf16x8*>(wb + vB[0]);
    bb[0][1] = *reinterpret_cast<const bf16x8*>(wb + vB[1]);

    f32x4 acc[4][2], accX[2];
    float bv0 = 0.f, bv1 = 0.f;

    #pragma unroll
    for (int s = 0; s < 32; ++s){
        const int cur = s & 1, nxt = cur ^ 1;
        const int cc = s >> 2, q = s & 3;

        if (s < 31){
            const int sn = s + 1, qn = sn & 3, ccn = sn >> 2;
            #pragma unroll
            for (int mi = 0; mi < 4; ++mi){
                unsigned ch = (pk[mi] >> (qn*8)) & 0xFFu;
                afb[nxt][mi] = *reinterpret_cast<const bf16x8*>(cb + ch*64 + lqoff);
            }
            axb[nxt] = *reinterpret_cast<const bf16x8*>(cb + voffX[qn]);
            bb[nxt][0] = *reinterpret_cast<const bf16x8*>(wb + ccn*16384 + vB[0] + qn*64);
            bb[nxt][1] = *reinterpret_cast<const bf16x8*>(wb + ccn*16384 + vB[1] + qn*64);
        }

        if (q == 0){
            f32x4 z = {0.f, 0.f, 0.f, 0.f};
            accX[0] = z; accX[1] = z;
            #pragma unroll
            for (int mi = 0; mi < 4; ++mi){ acc[mi][0] = z; acc[mi][1] = z; }
            bv0 = bias[cc*64 + colw + lr];
            bv1 = bias[cc*64 + colw + 16 + lr];
        }

        #pragma unroll
        for (int ni = 0; ni < 2; ++ni){
            #pragma unroll
            for (int mi = 0; mi < 4; ++mi)
                acc[mi][ni] = __builtin_amdgcn_mfma_f32_16x16x32_bf16(
                    afb[cur][mi], bb[cur][ni], acc[mi][ni], 0, 0, 0);
            accX[ni] = __builtin_amdgcn_mfma_f32_16x16x32_bf16(
                    axb[cur], bb[cur][ni], accX[ni], 0, 0, 0);
        }

        if (q == 3){
            // epilogue: max over t in registers (C: col=lr, row t=lq*4+reg)
            #pragma unroll
            for (int mi = 0; mi < 4; ++mi){
                int w = wy*4 + mi;
                float m0 = fmaxf(fmaxf(acc[mi][0][0], acc[mi][0][1]),
                                 fmaxf(acc[mi][0][2], acc[mi][0][3]));
                float m1 = fmaxf(fmaxf(acc[mi][1][0], acc[mi][1][1]),
                                 fmaxf(acc[mi][1][2], acc[mi][1][3]));
                // t=16: word w's value lives in lanes lq==wy, reg mi
                if (lq == wy){
                    m0 = fmaxf(m0, accX[0][mi]);
                    m1 = fmaxf(m1, accX[1][mi]);
                }
                m0 = fmaxf(m0, __shfl_xor(m0, 16, 64));
                m0 = fmaxf(m0, __shfl_xor(m0, 32, 64));
                m1 = fmaxf(m1, __shfl_xor(m1, 16, 64));
                m1 = fmaxf(m1, __shfl_xor(m1, 32, 64));
                m0 += bv0;
                m1 += bv1;
                if (lq < 2){
                    float mv = lq ? m1 : m0;
                    __builtin_nontemporal_store(
                        mv, &out[(wbase + w)*WEDIM + cc*64 + colw + lq*16 + lr]);
                }
            }
        }
    }
}

extern "C" void kernel_launch(void* const* d_in, const int* in_sizes, int n_in,
                              void* d_out, int out_size, void* d_ws, size_t ws_size,
                              hipStream_t stream) {
    const float* cemb     = (const float*)d_in[0];   // char_emb_w [256*32]
    const float* cnn      = (const float*)d_in[1];   // cnn_w [512*33*4]
    const int*   data     = (const int*)d_in[2];     // [16384]
    const int*   spelling = (const int*)d_in[3];     // [50000*20]
    float* outp = (float*)d_out;

    unsigned short* wbf    = (unsigned short*)d_ws;                       // 131072 B
    float*          bias   = (float*)((char*)d_ws + 131072);              // 2048 B
    unsigned short* cembbf = (unsigned short*)((char*)d_ws + 133120);     // 16448 B

    int prep_items = WEDIM*128 + 257*CEDIM + WEDIM;
    prep_kernel<<<dim3((prep_items + 255)/256), dim3(256), 0, stream>>>(cnn, cemb, wbf, cembbf, bias);
    conv_kernel<<<dim3(NBLK), dim3(256), 0, stream>>>(data, spelling, cembbf, wbf, bias, outp);
}

// Round 5
// 114.089 us; speedup vs baseline: 2.0314x; 2.0314x over previous
//
#include <hip/hip_runtime.h>
#include <hip/hip_bf16.h>
#include <cstdint>

// Problem constants
#define NWORDS 16384   // B*S
#define NCH    20      // chars per word
#define CEDIM  32      // char emb dim
#define WEDIM  512     // output channels
#define WPB    16      // words per block
#define NBLK   (NWORDS/WPB)   // 1024

#define AS3 __attribute__((address_space(3)))
#define AS1 __attribute__((address_space(1)))

typedef __attribute__((ext_vector_type(8))) short bf16x8;
typedef __attribute__((ext_vector_type(4))) float f32x4;

__device__ __forceinline__ unsigned short f2bf(float f){
    union { float f; unsigned int u; } v; v.f = f;
    unsigned int u = v.u + 0x7fffu + ((v.u >> 16) & 1u);
    return (unsigned short)(u >> 16);
}

// Prep v2:
//  wbf2: W pre-transposed k-chunk-major for coalesced LDS staging:
//    wbf2[((cc*16+kc)*64+col)*8 + j] = bf16(cnn[o=cc*64+col][i][k]),
//    kk=kc*8+j (kk = k*32+i; i=kk&31, k=kk>>5)
//  cembbf: [257][32] bf16, row 256 = zeros (t=16 tile padding)
//  bias[o] = sum_k cnn[o][32][k]   (lang-bit row folded to bias)
__global__ __launch_bounds__(256) void prep_kernel(const float* __restrict__ cnn,
                                                   const float* __restrict__ cemb,
                                                   unsigned short* __restrict__ wbf2,
                                                   unsigned short* __restrict__ cembbf,
                                                   float* __restrict__ bias){
    int idx = blockIdx.x * 256 + threadIdx.x;
    if (idx < 65536){
        int j  = idx & 7;
        int col= (idx >> 3) & 63;
        int kc = (idx >> 9) & 15;
        int cc = idx >> 13;
        int o  = cc*64 + col;
        int kk = kc*8 + j;
        int i  = kk & 31, k = kk >> 5;
        wbf2[idx] = f2bf(cnn[o*132 + i*4 + k]);
    } else if (idx < 65536 + 257*CEDIM){
        int r = idx - 65536;
        cembbf[r] = (r < 256*CEDIM) ? f2bf(cemb[r]) : (unsigned short)0;
    } else if (idx < 65536 + 257*CEDIM + WEDIM){
        int o = idx - (65536 + 257*CEDIM);
        const float* p = cnn + o*132 + 128;
        bias[o] = p[0] + p[1] + p[2] + p[3];
    }
}

// waves_per_eu(2,2): give allocator the full 256-reg budget (live ~217:
// af 64 + axf 16 + bb 16 + acc/accX 80 AGPR + addr). Round 4 proved that
// forcing 4 waves/EU spills ~100 MB of scratch; round 3 proved 2 waves
// with zero spill is the workable point for this live set.
__global__ __attribute__((amdgpu_waves_per_eu(2,2))) __launch_bounds__(256)
void conv_kernel(
    const int* __restrict__ data,              // [16384]
    const int* __restrict__ spelling,          // [50000][20]
    const unsigned short* __restrict__ cembbf, // [257][32] bf16 (row 256 = 0)
    const unsigned short* __restrict__ wbf2,   // [8][16][64][8] bf16 k-major
    const float* __restrict__ bias,            // [512]
    float* __restrict__ out)                   // [16384][512] f32
{
    __shared__ __align__(16) unsigned short sW[2][8192];  // 2 x 16 KB W tiles
    __shared__ int scid[WPB*NCH];                         // 320 ids

    const int tid   = threadIdx.x;
    const int wv    = tid >> 6;       // wave 0..3, owns words wv*4..wv*4+3
    const int lane  = tid & 63;
    const int lr    = lane & 15, lq = lane >> 4;
    const int wbase = blockIdx.x * WPB;

    // ---- stage W tile cc=0 (overlaps scid gather) ----
    {
        const unsigned short* gp0 = wbf2;   // cc=0
        #pragma unroll
        for (int t = 0; t < 4; ++t){
            int slot = wv*4 + t;            // kc slot 0..15
            const unsigned short* gp = gp0 + slot*512 + lane*8;
            unsigned short* lp = &sW[0][slot*512];
            __builtin_amdgcn_global_load_lds((const AS1 void*)gp, (AS3 void*)lp, 16, 0, 0);
        }
    }
    for (int s = tid; s < WPB*NCH; s += 256){
        int w = s / NCH, j = s - w*NCH;
        scid[s] = spelling[data[wbase + w]*NCH + j];
    }
    __syncthreads();

    const char* cb = (const char*)cembbf;
    const int lqoff = lq * 16;

    // ---- A fragments, resident: af[mi][q] for word wv*4+mi ----
    // lane (lr,lq) holds A[m=t=lr][kk'=q*32+lq*8+j] = cemb[scid[w*20+lr+q]][lq*8+j]
    bf16x8 af[4][4];
    #pragma unroll
    for (int mi = 0; mi < 4; ++mi){
        const int* sp = &scid[(wv*4 + mi)*NCH + lr];
        #pragma unroll
        for (int q = 0; q < 4; ++q)
            af[mi][q] = *reinterpret_cast<const bf16x8*>(cb + sp[q]*64 + lqoff);
    }
    // t=16 tile: rows 0..3 = this wave's words, rows 4..15 -> zero row 256
    bf16x8 axf[4];
    #pragma unroll
    for (int q = 0; q < 4; ++q){
        int ch = (lr < 4) ? scid[(wv*4 + lr)*NCH + 16 + q] : 256;
        axf[q] = *reinterpret_cast<const bf16x8*>(cb + ch*64 + lqoff);
    }

    const float* biasl = bias + lane;   // store lane covers col = cc*64 + lane

    #pragma unroll 1
    for (int cc = 0; cc < 8; ++cc){
        const int cur = cc & 1, nxt = cur ^ 1;

        // prefetch next W tile into other buffer (overlaps compute)
        if (cc < 7){
            const unsigned short* gp0 = wbf2 + (cc+1)*8192;
            #pragma unroll
            for (int t = 0; t < 4; ++t){
                int slot = wv*4 + t;
                const unsigned short* gp = gp0 + slot*512 + lane*8;
                unsigned short* lp = &sW[nxt][slot*512];
                __builtin_amdgcn_global_load_lds((const AS1 void*)gp, (AS3 void*)lp, 16, 0, 0);
            }
        }

        f32x4 acc[4][4], accX[4];
        {
            f32x4 z = {0.f, 0.f, 0.f, 0.f};
            #pragma unroll
            for (int ni = 0; ni < 4; ++ni){
                accX[ni] = z;
                #pragma unroll
                for (int mi = 0; mi < 4; ++mi) acc[mi][ni] = z;
            }
        }

        // compute: 64 main + 16 t16 MFMAs from sW[cur]
        #pragma unroll
        for (int q = 0; q < 4; ++q){
            // B frag: col = ni*16+lr, kc = q*4+lq, LDS k-major [kc][col][8]
            const unsigned short* wl = &sW[cur][(q*4 + lq)*512 + lr*8];
            bf16x8 bb[4];
            #pragma unroll
            for (int ni = 0; ni < 4; ++ni)
                bb[ni] = *reinterpret_cast<const bf16x8*>(wl + ni*128);
            #pragma unroll
            for (int ni = 0; ni < 4; ++ni){
                #pragma unroll
                for (int mi = 0; mi < 4; ++mi)
                    acc[mi][ni] = __builtin_amdgcn_mfma_f32_16x16x32_bf16(
                        af[mi][q], bb[ni], acc[mi][ni], 0, 0, 0);
                accX[ni] = __builtin_amdgcn_mfma_f32_16x16x32_bf16(
                        axf[q], bb[ni], accX[ni], 0, 0, 0);
            }
        }

        // epilogue: per word, max over t (regs + 2 shfl), one coalesced store
        float bv = biasl[cc*64];
        #pragma unroll
        for (int mi = 0; mi < 4; ++mi){
            float mred[4];
            #pragma unroll
            for (int ni = 0; ni < 4; ++ni){
                float m = fmaxf(fmaxf(acc[mi][ni][0], acc[mi][ni][1]),
                                fmaxf(acc[mi][ni][2], acc[mi][ni][3]));
                // t=16: word mi lives at lanes lq==0, reg mi of accX
                if (lq == 0) m = fmaxf(m, accX[ni][mi]);
                m = fmaxf(m, __shfl_xor(m, 16, 64));
                m = fmaxf(m, __shfl_xor(m, 32, 64));
                mred[ni] = m;
            }
            float mv = (lq == 0) ? mred[0] : (lq == 1) ? mred[1]
                     : (lq == 2) ? mred[2] : mred[3];
            __builtin_nontemporal_store(
                mv + bv, &out[(wbase + wv*4 + mi)*WEDIM + cc*64 + lane]);
        }

        __syncthreads();   // staging of nxt done; cur free for overwrite
    }
}

extern "C" void kernel_launch(void* const* d_in, const int* in_sizes, int n_in,
                              void* d_out, int out_size, void* d_ws, size_t ws_size,
                              hipStream_t stream) {
    const float* cemb     = (const float*)d_in[0];   // char_emb_w [256*32]
    const float* cnn      = (const float*)d_in[1];   // cnn_w [512*33*4]
    const int*   data     = (const int*)d_in[2];     // [16384]
    const int*   spelling = (const int*)d_in[3];     // [50000*20]
    float* outp = (float*)d_out;

    unsigned short* wbf2   = (unsigned short*)d_ws;                       // 131072 B
    float*          bias   = (float*)((char*)d_ws + 131072);              // 2048 B
    unsigned short* cembbf = (unsigned short*)((char*)d_ws + 133120);     // 16448 B

    int prep_items = 65536 + 257*CEDIM + WEDIM;   // 74272
    prep_kernel<<<dim3((prep_items + 255)/256), dim3(256), 0, stream>>>(cnn, cemb, wbf2, cembbf, bias);
    conv_kernel<<<dim3(NBLK), dim3(256), 0, stream>>>(data, spelling, cembbf, wbf2, bias, outp);
}